// Round 7
// baseline (438.058 us; speedup 1.0000x reference)
//
#include <hip/hip_runtime.h>

typedef __attribute__((ext_vector_type(8))) short short8;
typedef __attribute__((ext_vector_type(4))) short short4v;
typedef __attribute__((ext_vector_type(4))) float float4v;
typedef __attribute__((ext_vector_type(8))) __bf16 bf16x8;

// LDS layout (bytes):
//   region A  [0, 57344)        : XT bf16[49][512] (swizzled) during GEMMs; VT[8][64][56] after V
//   PQ        [57344, 107520)   : P_q bf16 flat s*128+dd*2 (pswz)   (50176 B)
//   PK        [107520, 157696)  : P_k same
//   attn ovl  [57344, 122880)   : per-head attn bf16 [64][64] swizzled (overlays PQ/PK after QK^T)
//   BIAS      [157696, 163104)  : bias_table f32 [169][8]
#define LDS_PQ 57344
#define LDS_PK 107520
#define LDS_BIAS 157696
#define LDS_TOTAL 163104

__device__ __forceinline__ unsigned short f2bf(float f) {
  unsigned u = __float_as_uint(f);
  u += 0x7FFFu + ((u >> 16) & 1u);   // RNE
  return (unsigned short)(u >> 16);
}

// P-region swizzle: store lanes vary t (s>>3), read lanes vary s -> both spread.
__device__ __forceinline__ int pswz(int s) { return ((s ^ (s >> 3)) & 7) << 4; }

// ---- kernel 1: convert q_w/k_w/v_w fp32 -> bf16 into workspace ----
__global__ void wconv_kernel(const float* __restrict__ qw, const float* __restrict__ kw,
                             const float* __restrict__ vw, short* __restrict__ out) {
  int g = blockIdx.x >> 8;  // 0:q 1:k 2:v
  const float* src = (g == 0) ? qw : (g == 1) ? kw : vw;
  int off = ((blockIdx.x & 255) * 256 + threadIdx.x) * 4;
  float4v v = *(const float4v*)(src + off);
  short4v o;
  o.x = (short)f2bf(v.x); o.y = (short)f2bf(v.y);
  o.z = (short)f2bf(v.z); o.w = (short)f2bf(v.w);
  *(short4v*)(out + g * 262144 + off) = o;
}

// ---- kernel 2: fused windowed attention, one 1024-thread workgroup per (b, window) ----
// 16 waves, 1 block/CU (LDS-capped), hard 128-reg/wave budget (round-3/5 lesson:
// register growth spills -> #pragma unroll 1 + 1-deep prefetch only).
// Round-7 changes:
//  (1) head-aligned GEMM split: wave w = (h = w&7, mh = w>>3) computes head h's
//      64 o-cols for row-half mh -> each wave reads only 2 A-tiles per kk
//      (A-LDS traffic halved; was: every wave read all 4 m-tiles).
//  (2) pswz(s) = ((s^(s>>3))&7)<<4 on PQ/PK: round-6's (s&7) was constant
//      across store lanes (s = t*8+h -> s&7 = h) giving a 16-way ds_write
//      conflict; s>>3 = t varies per store lane, s varies per read lane.
__global__ __launch_bounds__(1024, 4) void wattn_kernel(
    const float* __restrict__ x, const short* __restrict__ wcvt,
    const float* __restrict__ qb, const float* __restrict__ kb, const float* __restrict__ vb,
    const float* __restrict__ btab, float* __restrict__ out) {
  __shared__ __align__(16) char sm[LDS_TOTAL];
  const int tid  = threadIdx.x;
  const int lane = tid & 63;
  const int wave = tid >> 6;       // 0..15
  const int bwi  = blockIdx.x;     // b*64 + wi
  const int bb   = bwi >> 6, wi = bwi & 63;
  const int l15  = lane & 15;
  const int l4   = lane >> 4;
  const int ig   = l4 * 4;
  const int h    = wave & 7;       // head owned in both GEMM and attention phases
  const int mh   = wave >> 3;      // row-half owned

  // stage bias table (f32, 169*8)
  for (int i = tid; i < 169 * 8; i += 1024)
    *(float*)(sm + LDS_BIAS + i * 4) = btab[i];

  // stage x tile -> XT bf16 [49][512], row-XOR swizzle
  {
    const float* xb = x + (size_t)bb * (3136 * 512);
    const int whi = (wi >> 3) * 7, wlo = (wi & 7) * 7;
    for (int idx = tid; idx < 49 * 128; idx += 1024) {
      int t = idx >> 7, c4 = idx & 127;
      int yt = (t * 37) >> 8, xt = t - yt * 7;
      int l = (whi + yt) * 56 + wlo + xt;
      float4v v = *(const float4v*)(xb + l * 512 + c4 * 4);
      short4v o;
      o.x = (short)f2bf(v.x); o.y = (short)f2bf(v.y);
      o.z = (short)f2bf(v.z); o.w = (short)f2bf(v.w);
      int byte = t * 1024 + c4 * 8;
      *(short4v*)(sm + (byte ^ ((t & 7) << 4))) = o;
    }
  }
  __syncthreads();

  // A-fragment (XT) address components for this wave's 2 row-tiles
  int xbase[2], xsw[2];
#pragma unroll
  for (int mt = 0; mt < 2; ++mt) {
    int row = (mh * 2 + mt) * 16 + l15;   // rows >=49 read junk; discarded at store
    xbase[mt] = row * 1024;
    xsw[mt]   = (row & 7) << 4;
  }

  // ---- three projection GEMMs: P = XT @ W^T + b  (W as A-operand, swapped) ----
  for (int g = 0; g < 3; ++g) {
    const short* wt = wcvt + g * 262144;
    const float* bias = (g == 0) ? qb : (g == 1) ? kb : vb;
    float4v acc[4][2];   // [nt = o-tile within head][mt = row-tile]; D[row=o][col=t]
#pragma unroll
    for (int nt = 0; nt < 4; ++nt)
#pragma unroll
      for (int mt = 0; mt < 2; ++mt) acc[nt][mt] = (float4v)0.f;

    const short* wb = wt + (h * 64 + l15) * 512 + l4 * 8;
    bf16x8 wf[4];
#pragma unroll
    for (int nt = 0; nt < 4; ++nt)
      wf[nt] = __builtin_bit_cast(bf16x8, *(const short8*)(wb + nt * 8192));

#pragma unroll 1
    for (int kk = 0; kk < 16; ++kk) {
      const int nko = ((kk + 1) & 15) * 32;      // wraps; final prefetch discarded
      bf16x8 nw[4];
#pragma unroll
      for (int nt = 0; nt < 4; ++nt)
        nw[nt] = __builtin_bit_cast(bf16x8, *(const short8*)(wb + nt * 8192 + nko));
      const int c = kk * 64 + l4 * 16;
      bf16x8 xf[2];
#pragma unroll
      for (int mt = 0; mt < 2; ++mt)
        xf[mt] = __builtin_bit_cast(bf16x8, *(const short8*)(sm + xbase[mt] + (c ^ xsw[mt])));
#pragma unroll
      for (int nt = 0; nt < 4; ++nt)
#pragma unroll
        for (int mt = 0; mt < 2; ++mt)
          acc[nt][mt] = __builtin_amdgcn_mfma_f32_16x16x32_bf16(wf[nt], xf[mt], acc[nt][mt], 0, 0, 0);
#pragma unroll
      for (int nt = 0; nt < 4; ++nt) wf[nt] = nw[nt];
    }

    if (g < 2) {
      const int base = (g == 0) ? LDS_PQ : LDS_PK;
#pragma unroll
      for (int nt = 0; nt < 4; ++nt) {
        int o0 = h * 64 + nt * 16 + ig;          // o = o0 + r (all within head h)
        float4v bv = *(const float4v*)(bias + o0);
        int dd0 = nt * 16 + ig;
#pragma unroll
        for (int mt = 0; mt < 2; ++mt) {
          int t = (mh * 2 + mt) * 16 + l15;
          if (t < 49) {
            int s = t * 8 + h;
            short4v pk;
#pragma unroll
            for (int r = 0; r < 4; ++r) pk[r] = (short)f2bf(acc[nt][mt][r] + bv[r]);
            *(short4v*)(sm + base + ((s * 128 + dd0 * 2) ^ pswz(s))) = pk;
          }
        }
      }
    } else {
      __syncthreads();  // all waves done reading XT; region A becomes VT
#pragma unroll
      for (int nt = 0; nt < 4; ++nt) {
        int o0 = h * 64 + nt * 16 + ig;
        float4v bv = *(const float4v*)(bias + o0);
        int dd0 = nt * 16 + ig;
#pragma unroll
        for (int mt = 0; mt < 2; ++mt) {
          int t = (mh * 2 + mt) * 16 + l15;
          if (t < 49) {
            int s = t * 8 + h;
            int h2 = (s * 1339) >> 16;       // s / 49 (destination head)
            int tp = s - h2 * 49;
            char* p = sm + h2 * 7168 + tp * 2;
#pragma unroll
            for (int r = 0; r < 4; ++r)
              *(unsigned short*)(p + (dd0 + r) * 112) = f2bf(acc[nt][mt][r] + bv[r]);
          }
        }
      }
      // zero VT pads t' = 49..55 (0*NaN=NaN inside MFMA -> pads must be real zeros)
      if (tid < 512) {
        int h2 = tid >> 6, dd = tid & 63;
        char* p = sm + h2 * 7168 + dd * 112;
#pragma unroll
        for (int q = 49; q < 56; ++q) *(unsigned short*)(p + q * 2) = 0;
      }
      __syncthreads();
    }
  }

  // ---- attention: wave pair (h, h+8) -> head h; mh owns i-tiles {mh*2, mh*2+1} ----
  const float* bias_f = (const float*)(sm + LDS_BIAS);

  // QK^T swapped: D[row=j][col=i]; sc[jt][it], lane: i = (mh*2+it)*16+l15, j = jt*16+ig+r
  float4v sc[4][2];
#pragma unroll
  for (int jt = 0; jt < 4; ++jt)
#pragma unroll
    for (int it = 0; it < 2; ++it) sc[jt][it] = (float4v)0.f;

#pragma unroll
  for (int ks = 0; ks < 2; ++ks) {
    const int dd = ks * 32 + l4 * 8;
    bf16x8 kf[4], qf[2];
#pragma unroll
    for (int jt = 0; jt < 4; ++jt) {
      int s = h * 49 + jt * 16 + l15;            // rows >=49: junk, masked in softmax
      int flat = s * 128 + dd * 2;
      kf[jt] = __builtin_bit_cast(bf16x8, *(const short8*)(sm + LDS_PK + (flat ^ pswz(s))));
    }
#pragma unroll
    for (int it = 0; it < 2; ++it) {
      int s = h * 49 + (mh * 2 + it) * 16 + l15;
      int flat = s * 128 + dd * 2;
      qf[it] = __builtin_bit_cast(bf16x8, *(const short8*)(sm + LDS_PQ + (flat ^ pswz(s))));
    }
#pragma unroll
    for (int jt = 0; jt < 4; ++jt)
#pragma unroll
      for (int it = 0; it < 2; ++it)
        sc[jt][it] = __builtin_amdgcn_mfma_f32_16x16x32_bf16(kf[jt], qf[it], sc[jt][it], 0, 0, 0);
  }

  // softmax: lane holds 16 j-values (jt x r) of column i; reduce in-reg + shfl 16/32
#pragma unroll
  for (int it = 0; it < 2; ++it) {
    int i = (mh * 2 + it) * 16 + l15;
    int yi = (i * 37) >> 8, xi = i - yi * 7;
    float mx = -1e30f;
#pragma unroll
    for (int jt = 0; jt < 4; ++jt)
#pragma unroll
      for (int r = 0; r < 4; ++r) {
        int j = jt * 16 + ig + r;
        float v = -1e30f;
        if (i < 49 && j < 49) {
          int yj = (j * 37) >> 8, xj = j - yj * 7;
          int idx = (yi - yj + 6) * 13 + (xi - xj + 6);
          v = sc[jt][it][r] * 0.125f + bias_f[idx * 8 + h];
        }
        sc[jt][it][r] = v;
        mx = fmaxf(mx, v);
      }
    mx = fmaxf(mx, __shfl_xor(mx, 16));
    mx = fmaxf(mx, __shfl_xor(mx, 32));
    float ssum = 0.f;
#pragma unroll
    for (int jt = 0; jt < 4; ++jt)
#pragma unroll
      for (int r = 0; r < 4; ++r) {
        float e = __expf(sc[jt][it][r] - mx);    // -1e30 slots underflow to 0
        sc[jt][it][r] = e;
        ssum += e;
      }
    ssum += __shfl_xor(ssum, 16);
    ssum += __shfl_xor(ssum, 32);
    float inv = 1.f / ssum;
#pragma unroll
    for (int jt = 0; jt < 4; ++jt)
#pragma unroll
      for (int r = 0; r < 4; ++r) sc[jt][it][r] *= inv;
  }

  __syncthreads();  // Pq/Pk dead for ALL waves -> overlay attn (per head, [64][64] bf16 swizzled)
  const int ovb = LDS_PQ + h * 8192;
#pragma unroll
  for (int it = 0; it < 2; ++it) {
    int i = (mh * 2 + it) * 16 + l15;
    if (i < 49) {
      int rowb = i * 128;
      int swz = (i & 7) << 4;
#pragma unroll
      for (int jt = 0; jt < 4; ++jt) {
        short4v pk;
#pragma unroll
        for (int r = 0; r < 4; ++r) pk[r] = (short)f2bf(sc[jt][it][r]);
        *(short4v*)(sm + ovb + ((rowb + jt * 32 + ig * 2) ^ swz)) = pk;
      }
    }
  }
  __syncthreads();

  // PV swapped: A = VT (dd-tiles), B = attn (t-tiles); D[row=dd][col=t] = out^T
  float4v oacc[4][2];   // [dt][tt]
#pragma unroll
  for (int dt = 0; dt < 4; ++dt)
#pragma unroll
    for (int tt = 0; tt < 2; ++tt) oacc[dt][tt] = (float4v)0.f;

#pragma unroll
  for (int ks = 0; ks < 2; ++ks) {
    const int tp0 = ks * 32 + l4 * 8;
    const int tc  = (tp0 >= 56) ? 0 : tp0;  // clamp: attn cols >=49 are exact zeros
    bf16x8 vf[4], af[2];
#pragma unroll
    for (int dt = 0; dt < 4; ++dt) {
      int dd = dt * 16 + l15;
      vf[dt] = __builtin_bit_cast(bf16x8, *(const short8*)(sm + h * 7168 + dd * 112 + tc * 2));
    }
#pragma unroll
    for (int tt = 0; tt < 2; ++tt) {
      int t = (mh * 2 + tt) * 16 + l15;          // rows >=49: junk cols, discarded
      int flat = t * 128 + tp0 * 2;
      af[tt] = __builtin_bit_cast(bf16x8, *(const short8*)(sm + ovb + (flat ^ ((t & 7) << 4))));
    }
#pragma unroll
    for (int dt = 0; dt < 4; ++dt)
#pragma unroll
      for (int tt = 0; tt < 2; ++tt)
        oacc[dt][tt] = __builtin_amdgcn_mfma_f32_16x16x32_bf16(vf[dt], af[tt], oacc[dt][tt], 0, 0, 0);
  }

  // output: flat [b][wi][h][t'][dd]; float4 stores (r -> 4 consecutive dd)
  float* op = out + (size_t)bwi * 25088 + h * 3136;
#pragma unroll
  for (int tt = 0; tt < 2; ++tt) {
    int t = (mh * 2 + tt) * 16 + l15;
    if (t < 49) {
#pragma unroll
      for (int dt = 0; dt < 4; ++dt)
        *(float4v*)(op + t * 64 + dt * 16 + ig) = oacc[dt][tt];
    }
  }
}

extern "C" void kernel_launch(void* const* d_in, const int* in_sizes, int n_in,
                              void* d_out, int out_size, void* d_ws, size_t ws_size,
                              hipStream_t stream) {
  const float* x    = (const float*)d_in[0];
  const float* q_w  = (const float*)d_in[1];
  const float* q_b  = (const float*)d_in[2];
  const float* k_w  = (const float*)d_in[3];
  const float* k_b  = (const float*)d_in[4];
  const float* v_w  = (const float*)d_in[5];
  const float* v_b  = (const float*)d_in[6];
  const float* btab = (const float*)d_in[7];
  short* wcvt = (short*)d_ws;  // 3 * 512 * 512 bf16 = 1.5 MB

  hipLaunchKernelGGL(wconv_kernel, dim3(768), dim3(256), 0, stream, q_w, k_w, v_w, wcvt);
  hipLaunchKernelGGL(wattn_kernel, dim3(1024), dim3(1024), 0, stream,
                     x, wcvt, q_b, k_b, v_b, btab, (float*)d_out);
}

// Round 8
// 165.113 us; speedup vs baseline: 2.6531x; 2.6531x over previous
//
#include <hip/hip_runtime.h>

typedef __attribute__((ext_vector_type(8))) short short8;
typedef __attribute__((ext_vector_type(4))) short short4v;
typedef __attribute__((ext_vector_type(4))) float float4v;
typedef __attribute__((ext_vector_type(8))) __bf16 bf16x8;

// LDS layout (bytes):
//   region A  [0, 57344)        : XT bf16[49][512] (swizzled) during GEMMs; VT[8][64][56] after V
//   PQ        [57344, 107520)   : P_q bf16 flat s*128+dd*2 (pswz)   (50176 B)
//   PK        [107520, 157696)  : P_k same
//   attn ovl  [57344, 122880)   : per-head attn bf16 [64][64] swizzled (overlays PQ/PK after QK^T)
//   BIAS      [157696, 163104)  : bias_table f32 [169][8]
#define LDS_PQ 57344
#define LDS_PK 107520
#define LDS_BIAS 157696
#define LDS_TOTAL 163104

__device__ __forceinline__ unsigned short f2bf(float f) {
  unsigned u = __float_as_uint(f);
  u += 0x7FFFu + ((u >> 16) & 1u);   // RNE
  return (unsigned short)(u >> 16);
}

// P-region swizzle: store lanes vary t (s>>3), read lanes vary s -> both spread.
__device__ __forceinline__ int pswz(int s) { return ((s ^ (s >> 3)) & 7) << 4; }

// ---- kernel 1: convert + pre-swizzle q_w/k_w/v_w fp32 -> bf16 fragment order ----
// Output layout: [g][kk=16][wave=16][n01=2][lane=64][j=8] shorts, so in the GEMM
// a wave's fragment load is ONE contiguous 1-KB segment (64 lanes x 16 B) instead
// of a 16-cache-line gather (16 rows x 64 B at 1024-B stride).
// Element [g][kk][w][n01][lane][j] = W_g[o = w*32 + n01*16 + (lane&15)]
//                                       [k = kk*32 + (lane>>4)*8 + j]
__global__ void wconv_kernel(const float* __restrict__ qw, const float* __restrict__ kw,
                             const float* __restrict__ vw, short* __restrict__ out) {
  int idx = blockIdx.x * 256 + threadIdx.x;   // 3*32768 threads, 8 shorts each
  int g = idx >> 15;
  int rem = idx & 32767;                      // (((kk*16 + w)*2 + n01)*64 + lane)
  int lane = rem & 63;
  int n01 = (rem >> 6) & 1;
  int w   = (rem >> 7) & 15;
  int kk  = rem >> 11;
  int o  = w * 32 + n01 * 16 + (lane & 15);
  int k0 = kk * 32 + (lane >> 4) * 8;
  const float* src = (g == 0) ? qw : (g == 1) ? kw : vw;
  const float* p = src + o * 512 + k0;
  float4v v0 = *(const float4v*)(p);
  float4v v1 = *(const float4v*)(p + 4);
  short8 o8;
  o8[0] = (short)f2bf(v0.x); o8[1] = (short)f2bf(v0.y);
  o8[2] = (short)f2bf(v0.z); o8[3] = (short)f2bf(v0.w);
  o8[4] = (short)f2bf(v1.x); o8[5] = (short)f2bf(v1.y);
  o8[6] = (short)f2bf(v1.z); o8[7] = (short)f2bf(v1.w);
  *(short8*)(out + idx * 8) = o8;
}

// ---- kernel 2: fused windowed attention, one 1024-thread workgroup per (b, window) ----
// 16 waves, 1 block/CU (LDS-capped), hard 128-reg/wave budget.
// Validated laws: (r3/r5) any register growth spills -> #pragma unroll 1 +
// 1-deep prefetch only; (r7) GEMM loop tolerates 2 in-flight weight fragments
// per wave, 4 serializes it. GEMM split: wave owns 32 o-cols (wcol = wave*32),
// reads all 4 A-row-tiles. pswz on PQ/PK kills the 16-way P-store conflict.
__global__ __launch_bounds__(1024, 4) void wattn_kernel(
    const float* __restrict__ x, const short* __restrict__ wcvt,
    const float* __restrict__ qb, const float* __restrict__ kb, const float* __restrict__ vb,
    const float* __restrict__ btab, float* __restrict__ out) {
  __shared__ __align__(16) char sm[LDS_TOTAL];
  const int tid  = threadIdx.x;
  const int lane = tid & 63;
  const int wave = tid >> 6;       // 0..15
  const int bwi  = blockIdx.x;     // b*64 + wi
  const int bb   = bwi >> 6, wi = bwi & 63;
  const int l15  = lane & 15;
  const int l4   = lane >> 4;
  const int ig   = l4 * 4;

  // stage bias table (f32, 169*8)
  for (int i = tid; i < 169 * 8; i += 1024)
    *(float*)(sm + LDS_BIAS + i * 4) = btab[i];

  // stage x tile -> XT bf16 [49][512], row-XOR swizzle
  {
    const float* xb = x + (size_t)bb * (3136 * 512);
    const int whi = (wi >> 3) * 7, wlo = (wi & 7) * 7;
    for (int idx = tid; idx < 49 * 128; idx += 1024) {
      int t = idx >> 7, c4 = idx & 127;
      int yt = (t * 37) >> 8, xt = t - yt * 7;
      int l = (whi + yt) * 56 + wlo + xt;
      float4v v = *(const float4v*)(xb + l * 512 + c4 * 4);
      short4v o;
      o.x = (short)f2bf(v.x); o.y = (short)f2bf(v.y);
      o.z = (short)f2bf(v.z); o.w = (short)f2bf(v.w);
      int byte = t * 1024 + c4 * 8;
      *(short4v*)(sm + (byte ^ ((t & 7) << 4))) = o;
    }
  }
  __syncthreads();

  const int wcol = wave * 32;

  // XT (B-operand) fragment address components; rows >=49 read junk, discarded
  int xbase[4], xsw[4];
#pragma unroll
  for (int mt = 0; mt < 4; ++mt) {
    int row = mt * 16 + l15;
    xbase[mt] = row * 1024;
    xsw[mt]   = (row & 7) << 4;
  }

  // this wave's weight fragment stream (fragment-order layout, 1 KB contiguous each)
  const short* wgb0 = wcvt + wave * 1024 + lane * 8;          // n01 = 0
  // per g: + g*262144; per kk: + kk*16384; n01=1: +512

  // ---- three projection GEMMs: P = XT @ W^T + b  (W as A-operand, swapped) ----
  for (int g = 0; g < 3; ++g) {
    const short* wgb = wgb0 + g * 262144;
    const float* bias = (g == 0) ? qb : (g == 1) ? kb : vb;
    float4v acc[2][4];   // [nt = o-tile][mt = row-tile]; D[row=o][col=t]
#pragma unroll
    for (int nt = 0; nt < 2; ++nt)
#pragma unroll
      for (int mt = 0; mt < 4; ++mt) acc[nt][mt] = (float4v)0.f;

    bf16x8 w0 = __builtin_bit_cast(bf16x8, *(const short8*)(wgb));
    bf16x8 w1 = __builtin_bit_cast(bf16x8, *(const short8*)(wgb + 512));

#pragma unroll 1
    for (int kk = 0; kk < 16; ++kk) {
      const int nko = ((kk + 1) & 15) * 16384;   // wraps; final prefetch discarded
      bf16x8 nw0 = __builtin_bit_cast(bf16x8, *(const short8*)(wgb + nko));
      bf16x8 nw1 = __builtin_bit_cast(bf16x8, *(const short8*)(wgb + nko + 512));
      const int c = kk * 64 + l4 * 16;
      bf16x8 xf[4];
#pragma unroll
      for (int mt = 0; mt < 4; ++mt)
        xf[mt] = __builtin_bit_cast(bf16x8, *(const short8*)(sm + xbase[mt] + (c ^ xsw[mt])));
#pragma unroll
      for (int mt = 0; mt < 4; ++mt) {
        acc[0][mt] = __builtin_amdgcn_mfma_f32_16x16x32_bf16(w0, xf[mt], acc[0][mt], 0, 0, 0);
        acc[1][mt] = __builtin_amdgcn_mfma_f32_16x16x32_bf16(w1, xf[mt], acc[1][mt], 0, 0, 0);
      }
      w0 = nw0;
      w1 = nw1;
    }

    if (g < 2) {
      const int base = (g == 0) ? LDS_PQ : LDS_PK;
#pragma unroll
      for (int nt = 0; nt < 2; ++nt) {
        int o0 = wcol + nt * 16 + ig;            // o = o0 + r, r=0..3 (same head)
        float4v bv = *(const float4v*)(bias + o0);
        int dd0 = o0 & 63, sg = o0 >> 6;
#pragma unroll
        for (int mt = 0; mt < 4; ++mt) {
          int t = mt * 16 + l15;
          if (t < 49) {
            int s = t * 8 + sg;
            short4v pk;
#pragma unroll
            for (int r = 0; r < 4; ++r) pk[r] = (short)f2bf(acc[nt][mt][r] + bv[r]);
            *(short4v*)(sm + base + ((s * 128 + dd0 * 2) ^ pswz(s))) = pk;
          }
        }
      }
    } else {
      __syncthreads();  // all waves done reading XT; region A becomes VT
#pragma unroll
      for (int nt = 0; nt < 2; ++nt) {
        int o0 = wcol + nt * 16 + ig;
        float4v bv = *(const float4v*)(bias + o0);
        int dd0 = o0 & 63, sg = o0 >> 6;
#pragma unroll
        for (int mt = 0; mt < 4; ++mt) {
          int t = mt * 16 + l15;
          if (t < 49) {
            int s = t * 8 + sg;
            int h2 = (s * 1339) >> 16;       // s / 49 (destination head)
            int tp = s - h2 * 49;
            char* p = sm + h2 * 7168 + tp * 2;
#pragma unroll
            for (int r = 0; r < 4; ++r)
              *(unsigned short*)(p + (dd0 + r) * 112) = f2bf(acc[nt][mt][r] + bv[r]);
          }
        }
      }
      // zero VT pads t' = 49..55 (0*NaN=NaN inside MFMA -> pads must be real zeros)
      if (tid < 512) {
        int h2 = tid >> 6, dd = tid & 63;
        char* p = sm + h2 * 7168 + dd * 112;
#pragma unroll
        for (int q = 49; q < 56; ++q) *(unsigned short*)(p + q * 2) = 0;
      }
      __syncthreads();
    }
  }

  // ---- attention: wave pair (h, h+8) -> head h; mh owns i-tiles {mh*2, mh*2+1} ----
  const int h  = wave & 7;
  const int mh = wave >> 3;
  const float* bias_f = (const float*)(sm + LDS_BIAS);

  // QK^T swapped: D[row=j][col=i]; sc[jt][it], lane: i = (mh*2+it)*16+l15, j = jt*16+ig+r
  float4v sc[4][2];
#pragma unroll
  for (int jt = 0; jt < 4; ++jt)
#pragma unroll
    for (int it = 0; it < 2; ++it) sc[jt][it] = (float4v)0.f;

#pragma unroll
  for (int ks = 0; ks < 2; ++ks) {
    const int dd = ks * 32 + l4 * 8;
    bf16x8 kf[4], qf[2];
#pragma unroll
    for (int jt = 0; jt < 4; ++jt) {
      int s = h * 49 + jt * 16 + l15;            // rows >=49: junk, masked in softmax
      int flat = s * 128 + dd * 2;
      kf[jt] = __builtin_bit_cast(bf16x8, *(const short8*)(sm + LDS_PK + (flat ^ pswz(s))));
    }
#pragma unroll
    for (int it = 0; it < 2; ++it) {
      int s = h * 49 + (mh * 2 + it) * 16 + l15;
      int flat = s * 128 + dd * 2;
      qf[it] = __builtin_bit_cast(bf16x8, *(const short8*)(sm + LDS_PQ + (flat ^ pswz(s))));
    }
#pragma unroll
    for (int jt = 0; jt < 4; ++jt)
#pragma unroll
      for (int it = 0; it < 2; ++it)
        sc[jt][it] = __builtin_amdgcn_mfma_f32_16x16x32_bf16(kf[jt], qf[it], sc[jt][it], 0, 0, 0);
  }

  // softmax: lane holds 16 j-values (jt x r) of column i; reduce in-reg + shfl 16/32
#pragma unroll
  for (int it = 0; it < 2; ++it) {
    int i = (mh * 2 + it) * 16 + l15;
    int yi = (i * 37) >> 8, xi = i - yi * 7;
    float mx = -1e30f;
#pragma unroll
    for (int jt = 0; jt < 4; ++jt)
#pragma unroll
      for (int r = 0; r < 4; ++r) {
        int j = jt * 16 + ig + r;
        float v = -1e30f;
        if (i < 49 && j < 49) {
          int yj = (j * 37) >> 8, xj = j - yj * 7;
          int idx = (yi - yj + 6) * 13 + (xi - xj + 6);
          v = sc[jt][it][r] * 0.125f + bias_f[idx * 8 + h];
        }
        sc[jt][it][r] = v;
        mx = fmaxf(mx, v);
      }
    mx = fmaxf(mx, __shfl_xor(mx, 16));
    mx = fmaxf(mx, __shfl_xor(mx, 32));
    float ssum = 0.f;
#pragma unroll
    for (int jt = 0; jt < 4; ++jt)
#pragma unroll
      for (int r = 0; r < 4; ++r) {
        float e = __expf(sc[jt][it][r] - mx);    // -1e30 slots underflow to 0
        sc[jt][it][r] = e;
        ssum += e;
      }
    ssum += __shfl_xor(ssum, 16);
    ssum += __shfl_xor(ssum, 32);
    float inv = 1.f / ssum;
#pragma unroll
    for (int jt = 0; jt < 4; ++jt)
#pragma unroll
      for (int r = 0; r < 4; ++r) sc[jt][it][r] *= inv;
  }

  __syncthreads();  // Pq/Pk dead for ALL waves -> overlay attn (per head, [64][64] bf16 swizzled)
  const int ovb = LDS_PQ + h * 8192;
#pragma unroll
  for (int it = 0; it < 2; ++it) {
    int i = (mh * 2 + it) * 16 + l15;
    if (i < 49) {
      int rowb = i * 128;
      int swz = (i & 7) << 4;
#pragma unroll
      for (int jt = 0; jt < 4; ++jt) {
        short4v pk;
#pragma unroll
        for (int r = 0; r < 4; ++r) pk[r] = (short)f2bf(sc[jt][it][r]);
        *(short4v*)(sm + ovb + ((rowb + jt * 32 + ig * 2) ^ swz)) = pk;
      }
    }
  }
  __syncthreads();

  // PV swapped: A = VT (dd-tiles), B = attn (t-tiles); D[row=dd][col=t] = out^T
  float4v oacc[4][2];   // [dt][tt]
#pragma unroll
  for (int dt = 0; dt < 4; ++dt)
#pragma unroll
    for (int tt = 0; tt < 2; ++tt) oacc[dt][tt] = (float4v)0.f;

#pragma unroll
  for (int ks = 0; ks < 2; ++ks) {
    const int tp0 = ks * 32 + l4 * 8;
    const int tc  = (tp0 >= 56) ? 0 : tp0;  // clamp: attn cols >=49 are exact zeros
    bf16x8 vf[4], af[2];
#pragma unroll
    for (int dt = 0; dt < 4; ++dt) {
      int dd = dt * 16 + l15;
      vf[dt] = __builtin_bit_cast(bf16x8, *(const short8*)(sm + h * 7168 + dd * 112 + tc * 2));
    }
#pragma unroll
    for (int tt = 0; tt < 2; ++tt) {
      int t = (mh * 2 + tt) * 16 + l15;          // rows >=49: junk cols, discarded
      int flat = t * 128 + tp0 * 2;
      af[tt] = __builtin_bit_cast(bf16x8, *(const short8*)(sm + ovb + (flat ^ ((t & 7) << 4))));
    }
#pragma unroll
    for (int dt = 0; dt < 4; ++dt)
#pragma unroll
      for (int tt = 0; tt < 2; ++tt)
        oacc[dt][tt] = __builtin_amdgcn_mfma_f32_16x16x32_bf16(vf[dt], af[tt], oacc[dt][tt], 0, 0, 0);
  }

  // output: flat [b][wi][h][t'][dd]; float4 stores (r -> 4 consecutive dd)
  float* op = out + (size_t)bwi * 25088 + h * 3136;
#pragma unroll
  for (int tt = 0; tt < 2; ++tt) {
    int t = (mh * 2 + tt) * 16 + l15;
    if (t < 49) {
#pragma unroll
      for (int dt = 0; dt < 4; ++dt)
        *(float4v*)(op + t * 64 + dt * 16 + ig) = oacc[dt][tt];
    }
  }
}

extern "C" void kernel_launch(void* const* d_in, const int* in_sizes, int n_in,
                              void* d_out, int out_size, void* d_ws, size_t ws_size,
                              hipStream_t stream) {
  const float* x    = (const float*)d_in[0];
  const float* q_w  = (const float*)d_in[1];
  const float* q_b  = (const float*)d_in[2];
  const float* k_w  = (const float*)d_in[3];
  const float* k_b  = (const float*)d_in[4];
  const float* v_w  = (const float*)d_in[5];
  const float* v_b  = (const float*)d_in[6];
  const float* btab = (const float*)d_in[7];
  short* wcvt = (short*)d_ws;  // 3 * 512 * 512 bf16 = 1.5 MB, fragment-order layout

  hipLaunchKernelGGL(wconv_kernel, dim3(384), dim3(256), 0, stream, q_w, k_w, v_w, wcvt);
  hipLaunchKernelGGL(wattn_kernel, dim3(1024), dim3(1024), 0, stream,
                     x, wcvt, q_b, k_b, v_b, btab, (float*)d_out);
}

// Round 10
// 165.082 us; speedup vs baseline: 2.6536x; 1.0002x over previous
//
#include <hip/hip_runtime.h>

typedef __attribute__((ext_vector_type(8))) short short8;
typedef __attribute__((ext_vector_type(4))) short short4v;
typedef __attribute__((ext_vector_type(4))) float float4v;
typedef __attribute__((ext_vector_type(8))) __bf16 bf16x8;

// LDS layout (bytes):
//   region A  [0, 57344)        : XT bf16[49][512] (row-XOR swz) during GEMMs;
//                                 VT bf16[64][448] (= [dd][h*56+tp], XOR (dd&7)<<4) after V
//   PQ        [57344, 107520)   : P_q bf16, row s=8t+sg at s*128 (pswz). After softmax the
//                                 (h,mh) wave OVERLAYS attn in place into rows s=h*49+i.
//   PK        [107520, 157696)  : P_k same layout
//   BIAS      [157696, 163104)  : bias_table f32 [169][8]
#define LDS_PQ 57344
#define LDS_PK 107520
#define LDS_BIAS 157696
#define LDS_TOTAL 163104

__device__ __forceinline__ unsigned short f2bf(float f) {
  unsigned u = __float_as_uint(f);
  u += 0x7FFFu + ((u >> 16) & 1u);   // RNE
  return (unsigned short)(u >> 16);
}

// P-region swizzle: store lanes vary t (s>>3), read lanes vary s -> both spread.
__device__ __forceinline__ int pswz(int s) { return ((s ^ (s >> 3)) & 7) << 4; }

// ---- kernel 1: convert + pre-swizzle q_w/k_w/v_w fp32 -> bf16 fragment order ----
// [g][kk=16][wave=16][n01=2][lane=64][j=8] shorts: a wave's fragment load is one
// contiguous 1-KB segment (64 lanes x 16 B).
// Element = W_g[o = w*32 + n01*16 + (lane&15)][k = kk*32 + (lane>>4)*8 + j]
__global__ void wconv_kernel(const float* __restrict__ qw, const float* __restrict__ kw,
                             const float* __restrict__ vw, short* __restrict__ out) {
  int idx = blockIdx.x * 256 + threadIdx.x;   // 3*32768 threads, 8 shorts each
  int g = idx >> 15;
  int rem = idx & 32767;
  int lane = rem & 63;
  int n01 = (rem >> 6) & 1;
  int w   = (rem >> 7) & 15;
  int kk  = rem >> 11;
  int o  = w * 32 + n01 * 16 + (lane & 15);
  int k0 = kk * 32 + (lane >> 4) * 8;
  const float* src = (g == 0) ? qw : (g == 1) ? kw : vw;
  const float* p = src + o * 512 + k0;
  float4v v0 = *(const float4v*)(p);
  float4v v1 = *(const float4v*)(p + 4);
  short8 o8;
  o8[0] = (short)f2bf(v0.x); o8[1] = (short)f2bf(v0.y);
  o8[2] = (short)f2bf(v0.z); o8[3] = (short)f2bf(v0.w);
  o8[4] = (short)f2bf(v1.x); o8[5] = (short)f2bf(v1.y);
  o8[6] = (short)f2bf(v1.z); o8[7] = (short)f2bf(v1.w);
  *(short8*)(out + idx * 8) = o8;
}

// ---- kernel 2: fused windowed attention, one 1024-thread workgroup per (b, window) ----
// 16 waves, 1 block/CU (LDS-capped). Laws: (r3/r5) register growth spills ->
// rolled loops; (r7) weight-path must be coalesced; (r8) fragment-order weights.
// Round-10: round-9 structure (depth-2 weight prefetch, 3 barriers, in-place attn
// overlay, VT [dd][h*56+tp] layout, folded Q-scale) + the r9 NaN fix: VT junk
// cols tp=49..55 are never written by the V epilogue but ARE read by PV k-slots
// whose attn-B is 0.0 -- 0*NaN=NaN, so they must be zeroed explicitly.
__global__ __launch_bounds__(1024, 4) void wattn_kernel(
    const float* __restrict__ x, const short* __restrict__ wcvt,
    const float* __restrict__ qb, const float* __restrict__ kb, const float* __restrict__ vb,
    const float* __restrict__ btab, float* __restrict__ out) {
  __shared__ __align__(16) char sm[LDS_TOTAL];
  const int tid  = threadIdx.x;
  const int lane = tid & 63;
  const int wave = tid >> 6;       // 0..15
  const int bwi  = blockIdx.x;     // b*64 + wi
  const int bb   = bwi >> 6, wi = bwi & 63;
  const int l15  = lane & 15;
  const int l4   = lane >> 4;
  const int ig   = l4 * 4;

  // stage bias table (f32, 169*8)
  for (int i = tid; i < 169 * 8; i += 1024)
    *(float*)(sm + LDS_BIAS + i * 4) = btab[i];

  // stage x tile -> XT bf16 [49][512], row-XOR swizzle
  {
    const float* xb = x + (size_t)bb * (3136 * 512);
    const int whi = (wi >> 3) * 7, wlo = (wi & 7) * 7;
    for (int idx = tid; idx < 49 * 128; idx += 1024) {
      int t = idx >> 7, c4 = idx & 127;
      int yt = (t * 37) >> 8, xt = t - yt * 7;
      int l = (whi + yt) * 56 + wlo + xt;
      float4v v = *(const float4v*)(xb + l * 512 + c4 * 4);
      short4v o;
      o.x = (short)f2bf(v.x); o.y = (short)f2bf(v.y);
      o.z = (short)f2bf(v.z); o.w = (short)f2bf(v.w);
      int byte = t * 1024 + c4 * 8;
      *(short4v*)(sm + (byte ^ ((t & 7) << 4))) = o;
    }
  }
  __syncthreads();

  const int wcol = wave * 32;
  const int ck   = l4 * 16;

  // XT (B-operand) fragment address components; rows >=49 read junk, discarded
  int xbase[4], xsw[4];
#pragma unroll
  for (int mt = 0; mt < 4; ++mt) {
    int row = mt * 16 + l15;
    xbase[mt] = row * 1024;
    xsw[mt]   = (row & 7) << 4;
  }

  // this wave's weight fragment stream (fragment-order layout, 1 KB contiguous each)
  const short* wgb0 = wcvt + wave * 1024 + lane * 8;

#define LDW(OFF) __builtin_bit_cast(bf16x8, *(const short8*)(wgb + (OFF)))
#define GEMM_PHASE(KIDX, W0, W1)                                                          \
  do {                                                                                    \
    const int c_ = (KIDX) * 64 + ck;                                                      \
    bf16x8 x0_ = __builtin_bit_cast(bf16x8, *(const short8*)(sm + xbase[0] + (c_ ^ xsw[0]))); \
    bf16x8 x1_ = __builtin_bit_cast(bf16x8, *(const short8*)(sm + xbase[1] + (c_ ^ xsw[1]))); \
    bf16x8 x2_ = __builtin_bit_cast(bf16x8, *(const short8*)(sm + xbase[2] + (c_ ^ xsw[2]))); \
    bf16x8 x3_ = __builtin_bit_cast(bf16x8, *(const short8*)(sm + xbase[3] + (c_ ^ xsw[3]))); \
    acc[0][0] = __builtin_amdgcn_mfma_f32_16x16x32_bf16(W0, x0_, acc[0][0], 0, 0, 0);     \
    acc[1][0] = __builtin_amdgcn_mfma_f32_16x16x32_bf16(W1, x0_, acc[1][0], 0, 0, 0);     \
    acc[0][1] = __builtin_amdgcn_mfma_f32_16x16x32_bf16(W0, x1_, acc[0][1], 0, 0, 0);     \
    acc[1][1] = __builtin_amdgcn_mfma_f32_16x16x32_bf16(W1, x1_, acc[1][1], 0, 0, 0);     \
    acc[0][2] = __builtin_amdgcn_mfma_f32_16x16x32_bf16(W0, x2_, acc[0][2], 0, 0, 0);     \
    acc[1][2] = __builtin_amdgcn_mfma_f32_16x16x32_bf16(W1, x2_, acc[1][2], 0, 0, 0);     \
    acc[0][3] = __builtin_amdgcn_mfma_f32_16x16x32_bf16(W0, x3_, acc[0][3], 0, 0, 0);     \
    acc[1][3] = __builtin_amdgcn_mfma_f32_16x16x32_bf16(W1, x3_, acc[1][3], 0, 0, 0);     \
  } while (0)

  // ---- three projection GEMMs: P = XT @ W^T + b  (W as A-operand, swapped) ----
  for (int g = 0; g < 3; ++g) {
    const short* wgb = wgb0 + g * 262144;
    const float* bias = (g == 0) ? qb : (g == 1) ? kb : vb;
    float4v acc[2][4];   // [nt = o-tile][mt = row-tile]; D[row=o][col=t]
#pragma unroll
    for (int nt = 0; nt < 2; ++nt)
#pragma unroll
      for (int mt = 0; mt < 4; ++mt) acc[nt][mt] = (float4v)0.f;

    // depth-2 software pipeline: 4 slots (A,B,C,D), prefetch kk+2 ahead
    bf16x8 wa0 = LDW(0),         wa1 = LDW(512);
    bf16x8 wb0 = LDW(16384),     wb1 = LDW(16384 + 512);
    bf16x8 wc0, wc1, wd0, wd1;

#pragma unroll 1
    for (int kk = 0; kk < 16; kk += 4) {
      wc0 = LDW(((kk + 2) & 15) * 16384); wc1 = LDW(((kk + 2) & 15) * 16384 + 512);
      GEMM_PHASE(kk, wa0, wa1);
      wd0 = LDW(((kk + 3) & 15) * 16384); wd1 = LDW(((kk + 3) & 15) * 16384 + 512);
      GEMM_PHASE(kk + 1, wb0, wb1);
      wa0 = LDW(((kk + 4) & 15) * 16384); wa1 = LDW(((kk + 4) & 15) * 16384 + 512);
      GEMM_PHASE(kk + 2, wc0, wc1);
      wb0 = LDW(((kk + 5) & 15) * 16384); wb1 = LDW(((kk + 5) & 15) * 16384 + 512);
      GEMM_PHASE(kk + 3, wd0, wd1);
    }

    if (g < 2) {
      const int base = (g == 0) ? LDS_PQ : LDS_PK;
      const float qs = (g == 0) ? 0.125f : 1.0f;   // fold 1/sqrt(d) into Q
#pragma unroll
      for (int nt = 0; nt < 2; ++nt) {
        int o0 = wcol + nt * 16 + ig;            // o = o0 + r, r=0..3 (same head)
        float4v bv = *(const float4v*)(bias + o0);
        int dd0 = o0 & 63, sg = o0 >> 6;
#pragma unroll
        for (int mt = 0; mt < 4; ++mt) {
          int t = mt * 16 + l15;
          if (t < 49) {
            int s = t * 8 + sg;
            short4v pk;
#pragma unroll
            for (int r = 0; r < 4; ++r) pk[r] = (short)f2bf((acc[nt][mt][r] + bv[r]) * qs);
            *(short4v*)(sm + base + ((s * 128 + dd0 * 2) ^ pswz(s))) = pk;
          }
        }
      }
    } else {
      __syncthreads();  // all waves done reading XT; region A becomes VT [dd][h*56+tp]
#pragma unroll
      for (int nt = 0; nt < 2; ++nt) {
        int o0 = wcol + nt * 16 + ig;
        float4v bv = *(const float4v*)(bias + o0);
        int dd0 = o0 & 63, sg = o0 >> 6;
#pragma unroll
        for (int mt = 0; mt < 4; ++mt) {
          int t = mt * 16 + l15;
          if (t < 49) {
            int s = t * 8 + sg;
            int h2 = (s * 1339) >> 16;       // s / 49 (destination head)
            int colb = h2 * 112 + (s - h2 * 49) * 2;
#pragma unroll
            for (int r = 0; r < 4; ++r) {
              int dd = dd0 + r;
              *(unsigned short*)(sm + ((dd * 896 + colb) ^ ((dd & 7) << 4))) =
                  f2bf(acc[nt][mt][r] + bv[r]);
            }
          }
        }
      }
      // zero VT junk cols tp=49..55 of every head stripe: never written above,
      // read by PV k-slots whose attn-B is exactly 0 -- 0*NaN=NaN (r9 bug).
      if (tid < 512) {
        int h2 = tid >> 6, dd = tid & 63;
        int rowb = dd * 896 + h2 * 112;
        int swz = (dd & 7) << 4;
#pragma unroll
        for (int q = 49; q < 56; ++q)
          *(unsigned short*)(sm + ((rowb + q * 2) ^ swz)) = 0;
      }
      // VT-ready sync happens after softmax, just before PV
    }
  }

  // ---- attention: wave pair (h, h+8) -> head h; mh owns i-tiles {mh*2, mh*2+1} ----
  const int h  = wave & 7;
  const int mh = wave >> 3;
  const float* bias_f = (const float*)(sm + LDS_BIAS);

  // QK^T swapped: D[row=j][col=i]; sc[jt][it], lane: i = (mh*2+it)*16+l15, j = jt*16+ig+r
  float4v sc[4][2];
#pragma unroll
  for (int jt = 0; jt < 4; ++jt)
#pragma unroll
    for (int it = 0; it < 2; ++it) sc[jt][it] = (float4v)0.f;

#pragma unroll
  for (int ks = 0; ks < 2; ++ks) {
    const int dd = ks * 32 + l4 * 8;
    bf16x8 kf[4], qf[2];
#pragma unroll
    for (int jt = 0; jt < 4; ++jt) {
      int s = h * 49 + jt * 16 + l15;            // rows beyond head: junk, masked by index
      int flat = s * 128 + dd * 2;
      kf[jt] = __builtin_bit_cast(bf16x8, *(const short8*)(sm + LDS_PK + (flat ^ pswz(s))));
    }
#pragma unroll
    for (int it = 0; it < 2; ++it) {
      int s = h * 49 + (mh * 2 + it) * 16 + l15;
      int flat = s * 128 + dd * 2;
      qf[it] = __builtin_bit_cast(bf16x8, *(const short8*)(sm + LDS_PQ + (flat ^ pswz(s))));
    }
#pragma unroll
    for (int jt = 0; jt < 4; ++jt)
#pragma unroll
      for (int it = 0; it < 2; ++it)
        sc[jt][it] = __builtin_amdgcn_mfma_f32_16x16x32_bf16(kf[jt], qf[it], sc[jt][it], 0, 0, 0);
  }

  // softmax: lane holds 16 j-values (jt x r) of column i; reduce in-reg + shfl 16/32
  // (scores already scaled: Q was pre-multiplied by 0.125 at its epilogue)
#pragma unroll
  for (int it = 0; it < 2; ++it) {
    int i = (mh * 2 + it) * 16 + l15;
    int yi = (i * 37) >> 8, xi = i - yi * 7;
    float mx = -1e30f;
#pragma unroll
    for (int jt = 0; jt < 4; ++jt)
#pragma unroll
      for (int r = 0; r < 4; ++r) {
        int j = jt * 16 + ig + r;
        float v = -1e30f;
        if (i < 49 && j < 49) {
          int yj = (j * 37) >> 8, xj = j - yj * 7;
          int idx = (yi - yj + 6) * 13 + (xi - xj + 6);
          v = sc[jt][it][r] + bias_f[idx * 8 + h];
        }
        sc[jt][it][r] = v;
        mx = fmaxf(mx, v);
      }
    mx = fmaxf(mx, __shfl_xor(mx, 16));
    mx = fmaxf(mx, __shfl_xor(mx, 32));
    float ssum = 0.f;
#pragma unroll
    for (int jt = 0; jt < 4; ++jt)
#pragma unroll
      for (int r = 0; r < 4; ++r) {
        float e = __expf(sc[jt][it][r] - mx);    // -1e30 slots underflow to 0
        sc[jt][it][r] = e;
        ssum += e;
      }
    ssum += __shfl_xor(ssum, 16);
    ssum += __shfl_xor(ssum, 32);
    float inv = 1.f / ssum;
#pragma unroll
    for (int jt = 0; jt < 4; ++jt)
#pragma unroll
      for (int r = 0; r < 4; ++r) sc[jt][it][r] *= inv;
  }

  // overlay attn IN PLACE into head h's own P_q rows (s = h*49+i). Only the
  // (h,*) pair validly reads these rows and each wave overwrites exactly the
  // rows it owns; cross-head stragglers read them only as masked junk (finite).
#pragma unroll
  for (int it = 0; it < 2; ++it) {
    int i = (mh * 2 + it) * 16 + l15;
    if (i < 49) {
      int s = h * 49 + i;
      int rowb = s * 128;
      int swz = pswz(s);
#pragma unroll
      for (int jt = 0; jt < 4; ++jt) {
        short4v pk;
#pragma unroll
        for (int r = 0; r < 4; ++r) pk[r] = (short)f2bf(sc[jt][it][r]);
        *(short4v*)(sm + LDS_PQ + ((rowb + jt * 32 + ig * 2) ^ swz)) = pk;
      }
    }
  }

  __syncthreads();  // VT (incl. pad zeros) + all overlays complete before PV

  // PV swapped: A = VT[dd][h*56+tp] (dt-tiles), B = attn rows (tt-tiles); D = out^T
  float4v oacc[4][2];   // [dt][tt]
#pragma unroll
  for (int dt = 0; dt < 4; ++dt)
#pragma unroll
    for (int tt = 0; tt < 2; ++tt) oacc[dt][tt] = (float4v)0.f;

#pragma unroll
  for (int ks = 0; ks < 2; ++ks) {
    const int tp0 = ks * 32 + l4 * 8;     // tp 56..63 lands in next stripe: finite x zero-B
    bf16x8 vf[4], af[2];
#pragma unroll
    for (int dt = 0; dt < 4; ++dt) {
      int dd = dt * 16 + l15;
      vf[dt] = __builtin_bit_cast(bf16x8,
          *(const short8*)(sm + ((dd * 896 + h * 112 + tp0 * 2) ^ ((dd & 7) << 4))));
    }
#pragma unroll
    for (int tt = 0; tt < 2; ++tt) {
      int t = (mh * 2 + tt) * 16 + l15;
      int tr = (t > 48) ? 48 : t;         // junk cols (t>=49) read row 48; discarded
      int s = h * 49 + tr;
      af[tt] = __builtin_bit_cast(bf16x8,
          *(const short8*)(sm + LDS_PQ + ((s * 128 + tp0 * 2) ^ pswz(s))));
    }
#pragma unroll
    for (int dt = 0; dt < 4; ++dt)
#pragma unroll
      for (int tt = 0; tt < 2; ++tt)
        oacc[dt][tt] = __builtin_amdgcn_mfma_f32_16x16x32_bf16(vf[dt], af[tt], oacc[dt][tt], 0, 0, 0);
  }

  // output: flat [b][wi][h][t'][dd]; float4 stores (r -> 4 consecutive dd)
  float* op = out + (size_t)bwi * 25088 + h * 3136;
#pragma unroll
  for (int tt = 0; tt < 2; ++tt) {
    int t = (mh * 2 + tt) * 16 + l15;
    if (t < 49) {
#pragma unroll
      for (int dt = 0; dt < 4; ++dt)
        *(float4v*)(op + t * 64 + dt * 16 + ig) = oacc[dt][tt];
    }
  }
#undef LDW
#undef GEMM_PHASE
}

extern "C" void kernel_launch(void* const* d_in, const int* in_sizes, int n_in,
                              void* d_out, int out_size, void* d_ws, size_t ws_size,
                              hipStream_t stream) {
  const float* x    = (const float*)d_in[0];
  const float* q_w  = (const float*)d_in[1];
  const float* q_b  = (const float*)d_in[2];
  const float* k_w  = (const float*)d_in[3];
  const float* k_b  = (const float*)d_in[4];
  const float* v_w  = (const float*)d_in[5];
  const float* v_b  = (const float*)d_in[6];
  const float* btab = (const float*)d_in[7];
  short* wcvt = (short*)d_ws;  // 3 * 512 * 512 bf16 = 1.5 MB, fragment-order layout

  hipLaunchKernelGGL(wconv_kernel, dim3(384), dim3(256), 0, stream, q_w, k_w, v_w, wcvt);
  hipLaunchKernelGGL(wattn_kernel, dim3(1024), dim3(1024), 0, stream,
                     x, wcvt, q_b, k_b, v_b, btab, (float*)d_out);
}